// Round 1
// baseline (26005.344 us; speedup 1.0000x reference)
//
#include <hip/hip_runtime.h>
#include <cstdint>
#include <cstddef>

// Problem constants
#define BB 256     // batch
#define TT 512     // time steps
#define INP 256    // input feature size
#define LL 8       // gumbel groups
#define CC 16      // categories per group
#define HH 512     // hidden
#define K0 896     // layer0 K = IN + L*C + H = 256+128+512
#define K1 1024    // layer1 K = H + H
// TAU = 0.1 (divide, matching reference)

// Noise mode: 1 = jax_threefry_partitionable (modern JAX default), 0 = legacy split-iota
#define NOISE_PARTITIONABLE 1

typedef _Float16 f16;
typedef _Float16 f16x8 __attribute__((ext_vector_type(8)));
typedef float f32x4 __attribute__((ext_vector_type(4)));

// ---------------- threefry2x32 (key = (0,42)) ----------------
__device__ __forceinline__ void tf_round(uint32_t& x0, uint32_t& x1, const int r) {
  x0 += x1;
  x1 = (x1 << r) | (x1 >> (32 - r));
  x1 ^= x0;
}

__device__ __forceinline__ void threefry2x32(uint32_t c0, uint32_t c1, uint32_t& o0, uint32_t& o1) {
  const uint32_t ks0 = 0u, ks1 = 42u;
  const uint32_t ks2 = 0x1BD11BDAu ^ ks0 ^ ks1;
  uint32_t x0 = c0 + ks0, x1 = c1 + ks1;
  tf_round(x0,x1,13); tf_round(x0,x1,15); tf_round(x0,x1,26); tf_round(x0,x1,6);
  x0 += ks1; x1 += ks2 + 1u;
  tf_round(x0,x1,17); tf_round(x0,x1,29); tf_round(x0,x1,16); tf_round(x0,x1,24);
  x0 += ks2; x1 += ks0 + 2u;
  tf_round(x0,x1,13); tf_round(x0,x1,15); tf_round(x0,x1,26); tf_round(x0,x1,6);
  x0 += ks0; x1 += ks1 + 3u;
  tf_round(x0,x1,17); tf_round(x0,x1,29); tf_round(x0,x1,16); tf_round(x0,x1,24);
  x0 += ks1; x1 += ks2 + 4u;
  tf_round(x0,x1,13); tf_round(x0,x1,15); tf_round(x0,x1,26); tf_round(x0,x1,6);
  x0 += ks2; x1 += ks0 + 5u;
  o0 = x0; o1 = x1;
}

// gumbel noise for flat index into (T,B,L,C), matching jax.random.gumbel(key(42))
__device__ __forceinline__ float gumbel_noise(uint32_t idx) {
  uint32_t bits;
#if NOISE_PARTITIONABLE
  uint32_t o0, o1;
  threefry2x32(0u, idx, o0, o1);   // counts = (hi=0, lo=idx)
  bits = o0 ^ o1;
#else
  const uint32_t HALFN = 1u << 23;   // total size 2^24 split in half
  uint32_t o0, o1;
  if (idx < HALFN) { threefry2x32(idx, idx + HALFN, o0, o1); bits = o0; }
  else             { threefry2x32(idx - HALFN, idx, o0, o1); bits = o1; }
#endif
  uint32_t fb = (bits >> 9) | 0x3f800000u;
  float u = __uint_as_float(fb) - 1.0f;       // [0,1)
  const float tiny = 1.17549435e-38f;
  u = fmaxf(tiny, u + tiny);                  // uniform(minval=tiny, maxval=1)
  return -logf(-logf(u));
}

// ---------------- setup: f16 weight conversion + state init ----------------
__global__ void setup_kernel(
    const float* __restrict__ Wih0, const float* __restrict__ Whh0,
    const float* __restrict__ bih0, const float* __restrict__ bhh0,
    const float* __restrict__ Wih1, const float* __restrict__ Whh1,
    const float* __restrict__ bih1, const float* __restrict__ bhh1,
    const float* __restrict__ Wlin,
    f16* __restrict__ W0c, f16* __restrict__ W1c, f16* __restrict__ Wlc,
    float* __restrict__ b0c, float* __restrict__ b1c,
    f16* __restrict__ h0, f16* __restrict__ h1,
    float* __restrict__ c0, float* __restrict__ c1,
    f16* __restrict__ ct)
{
  const uint32_t tid = blockIdx.x * blockDim.x + threadIdx.x;
  const uint32_t stride = gridDim.x * blockDim.x;
  // W0c: [2048][896] = [Wih0 | Whh0] per gate-row
  for (uint32_t e = tid; e < 2048u * 896u; e += stride) {
    uint32_t n = e / 896u, k = e % 896u;
    float v = (k < 384u) ? Wih0[n * 384u + k] : Whh0[n * 512u + (k - 384u)];
    W0c[e] = (f16)v;
  }
  // W1c: [2048][1024] = [Wih1 | Whh1]
  for (uint32_t e = tid; e < 2048u * 1024u; e += stride) {
    uint32_t n = e >> 10, k = e & 1023u;
    float v = (k < 512u) ? Wih1[(n << 9) + k] : Whh1[(n << 9) + (k - 512u)];
    W1c[e] = (f16)v;
  }
  for (uint32_t e = tid; e < 128u * 512u; e += stride) Wlc[e] = (f16)Wlin[e];
  for (uint32_t e = tid; e < 2048u; e += stride) {
    b0c[e] = bih0[e] + bhh0[e];
    b1c[e] = bih1[e] + bhh1[e];
  }
  for (uint32_t e = tid; e < 2u * BB * HH; e += stride) {
    h0[e] = (f16)0.f; h1[e] = (f16)0.f; c0[e] = 0.f; c1[e] = 0.f;
  }
  // ct init: one-hot(0) per group of 16
  for (uint32_t e = tid; e < 2u * BB * 128u; e += stride) {
    ct[e] = (f16)(((e & 15u) == 0u) ? 1.f : 0.f);
  }
}

// ---------------- fused gates GEMM + LSTM cell ----------------
__device__ __forceinline__ f16x8 cvt_f32x8_f16(const float* __restrict__ p) {
  f32x4 a = *(const f32x4*)p;
  f32x4 b = *(const f32x4*)(p + 4);
  f16x8 r;
  r[0] = (f16)a[0]; r[1] = (f16)a[1]; r[2] = (f16)a[2]; r[3] = (f16)a[3];
  r[4] = (f16)b[0]; r[5] = (f16)b[1]; r[6] = (f16)b[2]; r[7] = (f16)b[3];
  return r;
}

// Grid: 128 WGs = 8 M-tiles(32 rows) x 16 N-tiles(32 h-cols). Block: 256 = 4 waves.
// Wave w computes gate quadrant w (i,f,g,o) for its [32 x 32] tile; epilogue does the cell.
// LAYER 0: A = [states_t(256) | ct(128) | h0_prev(512)]   K=896
// LAYER 1: A = [h0_new(512) | h1_prev(512)]               K=1024
template<int LAYER>
__global__ __launch_bounds__(256) void lstm_kernel(
    int t,
    const float* __restrict__ states,
    const f16* __restrict__ seg1,
    const f16* __restrict__ seg2,
    const f16* __restrict__ W,     // [2048][K]
    const float* __restrict__ bc,  // combined bias [2048]
    const float* __restrict__ c_in,
    float* __restrict__ c_out,
    f16* __restrict__ h_out)
{
  constexpr int K = LAYER ? K1 : K0;
  const int mtile = blockIdx.x & 7;
  const int ntile = blockIdx.x >> 3;
  const int wave = threadIdx.x >> 6;
  const int lane = threadIdx.x & 63;
  const int m0 = mtile * 32;
  const int hcol0 = ntile * 32;
  const int g0 = wave * HH + hcol0;     // gate-col base for this wave's quadrant

  const int ra = lane & 15;
  const int kg = (lane >> 4) << 3;      // k group offset: 0,8,16,24
  const int r0 = m0 + ra;
  const int r1 = m0 + 16 + ra;

  f32x4 acc00 = {}, acc01 = {}, acc10 = {}, acc11 = {};

  #pragma unroll 4
  for (int ks = 0; ks < K / 32; ++ks) {
    const int k = ks * 32 + kg;
    f16x8 a0, a1;
    if (LAYER == 0) {
      if (k < INP) {
        a0 = cvt_f32x8_f16(states + ((size_t)r0 * TT + t) * INP + k);
        a1 = cvt_f32x8_f16(states + ((size_t)r1 * TT + t) * INP + k);
      } else if (k < INP + 128) {
        a0 = *(const f16x8*)(seg1 + r0 * 128 + (k - INP));
        a1 = *(const f16x8*)(seg1 + r1 * 128 + (k - INP));
      } else {
        a0 = *(const f16x8*)(seg2 + r0 * HH + (k - 384));
        a1 = *(const f16x8*)(seg2 + r1 * HH + (k - 384));
      }
    } else {
      if (k < HH) {
        a0 = *(const f16x8*)(seg1 + r0 * HH + k);
        a1 = *(const f16x8*)(seg1 + r1 * HH + k);
      } else {
        a0 = *(const f16x8*)(seg2 + r0 * HH + (k - HH));
        a1 = *(const f16x8*)(seg2 + r1 * HH + (k - HH));
      }
    }
    f16x8 b0 = *(const f16x8*)(W + (size_t)(g0 + ra) * K + k);
    f16x8 b1 = *(const f16x8*)(W + (size_t)(g0 + 16 + ra) * K + k);
    acc00 = __builtin_amdgcn_mfma_f32_16x16x32_f16(a0, b0, acc00, 0, 0, 0);
    acc01 = __builtin_amdgcn_mfma_f32_16x16x32_f16(a0, b1, acc01, 0, 0, 0);
    acc10 = __builtin_amdgcn_mfma_f32_16x16x32_f16(a1, b0, acc10, 0, 0, 0);
    acc11 = __builtin_amdgcn_mfma_f32_16x16x32_f16(a1, b1, acc11, 0, 0, 0);
  }

  // C/D layout: col = lane&15, row = (lane>>4)*4 + reg  [m89-verified]
  __shared__ float glds[4][32][33];
  const int crow = (lane >> 4) << 2;
  const int ccol = lane & 15;
  #pragma unroll
  for (int r = 0; r < 4; ++r) {
    glds[wave][crow + r][ccol]          = acc00[r];
    glds[wave][crow + r][16 + ccol]     = acc01[r];
    glds[wave][16 + crow + r][ccol]     = acc10[r];
    glds[wave][16 + crow + r][16 + ccol]= acc11[r];
  }
  __syncthreads();

  // cell epilogue: 32x32 elements, 256 threads x 4
  const int m = threadIdx.x >> 3;
  const int n4 = (threadIdx.x & 7) << 2;
  const int brow = m0 + m;
  #pragma unroll
  for (int e = 0; e < 4; ++e) {
    const int n = n4 + e;
    const int hcol = hcol0 + n;
    float ii = glds[0][m][n] + bc[hcol];
    float ff = glds[1][m][n] + bc[HH + hcol];
    float gg = glds[2][m][n] + bc[2 * HH + hcol];
    float oo = glds[3][m][n] + bc[3 * HH + hcol];
    float si = 1.0f / (1.0f + expf(-ii));
    float sf = 1.0f / (1.0f + expf(-ff));
    float so = 1.0f / (1.0f + expf(-oo));
    float cn = sf * c_in[brow * HH + hcol] + si * tanhf(gg);
    c_out[brow * HH + hcol] = cn;
    h_out[brow * HH + hcol] = (f16)(so * tanhf(cn));
  }
}

// ---------------- q = h1 @ Wlin^T + b, gumbel softmax, write out + ct ----------------
__global__ __launch_bounds__(128) void qsm_kernel(
    int t,
    const f16* __restrict__ h1n,   // [256][512]
    const f16* __restrict__ Wl,    // [128][512]
    const float* __restrict__ blin,
    float* __restrict__ out,       // [B][T][128]
    f16* __restrict__ ct_out)      // [256][128]
{
  const int b = blockIdx.x;
  __shared__ __align__(16) f16 hl[HH];
  const int tid = threadIdx.x;
  for (int i = tid; i < HH; i += 128) hl[i] = h1n[b * HH + i];
  __syncthreads();

  float acc = 0.f;
  const f16* wrow = Wl + tid * HH;
  #pragma unroll 8
  for (int k = 0; k < HH; k += 8) {
    f16x8 w = *(const f16x8*)(wrow + k);
    f16x8 h = *(const f16x8*)(&hl[k]);
    #pragma unroll
    for (int j = 0; j < 8; ++j) acc += (float)h[j] * (float)w[j];
  }
  float qv = acc + blin[tid];

  const int l = tid >> 4;
  const uint32_t idx = (((uint32_t)t * BB + (uint32_t)b) * LL + (uint32_t)l) * CC + (uint32_t)(tid & 15);
  float logit = (qv + gumbel_noise(idx)) / 0.1f;

  float mx = logit;
  #pragma unroll
  for (int msk = 1; msk < 16; msk <<= 1) mx = fmaxf(mx, __shfl_xor(mx, msk, 16));
  float ex = expf(logit - mx);
  float sm = ex;
  #pragma unroll
  for (int msk = 1; msk < 16; msk <<= 1) sm += __shfl_xor(sm, msk, 16);
  float y = ex / sm;

  out[((size_t)b * TT + t) * 128 + tid] = y;
  ct_out[b * 128 + tid] = (f16)y;
}

// ---------------- host ----------------
extern "C" void kernel_launch(void* const* d_in, const int* in_sizes, int n_in,
                              void* d_out, int out_size, void* d_ws, size_t ws_size,
                              hipStream_t stream) {
  const float* states = (const float*)d_in[0];
  const float* Wih0 = (const float*)d_in[1];
  const float* Whh0 = (const float*)d_in[2];
  const float* bih0 = (const float*)d_in[3];
  const float* bhh0 = (const float*)d_in[4];
  const float* Wih1 = (const float*)d_in[5];
  const float* Whh1 = (const float*)d_in[6];
  const float* bih1 = (const float*)d_in[7];
  const float* bhh1 = (const float*)d_in[8];
  const float* Wlin = (const float*)d_in[9];
  const float* blin = (const float*)d_in[10];
  float* out = (float*)d_out;

  char* ws = (char*)d_ws;
  size_t off = 0;
  auto alloc = [&](size_t bytes) -> void* {
    void* p = ws + off;
    off += (bytes + 255) & ~(size_t)255;
    return p;
  };
  f16*  W0c = (f16*)alloc(2048ull * 896 * 2);
  f16*  W1c = (f16*)alloc(2048ull * 1024 * 2);
  f16*  Wlc = (f16*)alloc(128ull * 512 * 2);
  float* b0c = (float*)alloc(2048 * 4);
  float* b1c = (float*)alloc(2048 * 4);
  f16*  h0  = (f16*)alloc(2ull * BB * HH * 2);
  f16*  h1  = (f16*)alloc(2ull * BB * HH * 2);
  float* c0 = (float*)alloc(2ull * BB * HH * 4);
  float* c1 = (float*)alloc(2ull * BB * HH * 4);
  f16*  ct  = (f16*)alloc(2ull * BB * 128 * 2);
  (void)ws_size; (void)in_sizes; (void)n_in; (void)out_size;

  setup_kernel<<<1024, 256, 0, stream>>>(Wih0, Whh0, bih0, bhh0, Wih1, Whh1, bih1, bhh1,
                                         Wlin, W0c, W1c, Wlc, b0c, b1c, h0, h1, c0, c1, ct);

  for (int t = 0; t < TT; ++t) {
    const int p = t & 1, q = p ^ 1;
    lstm_kernel<0><<<128, 256, 0, stream>>>(
        t, states,
        ct + (size_t)p * BB * 128,        // seg1: ct_prev
        h0 + (size_t)p * BB * HH,         // seg2: h0_prev
        W0c, b0c,
        c0 + (size_t)p * BB * HH, c0 + (size_t)q * BB * HH,
        h0 + (size_t)q * BB * HH);        // -> h0_new
    lstm_kernel<1><<<128, 256, 0, stream>>>(
        t, nullptr,
        h0 + (size_t)q * BB * HH,         // seg1: h0_new
        h1 + (size_t)p * BB * HH,         // seg2: h1_prev
        W1c, b1c,
        c1 + (size_t)p * BB * HH, c1 + (size_t)q * BB * HH,
        h1 + (size_t)q * BB * HH);        // -> h1_new
    qsm_kernel<<<BB, 128, 0, stream>>>(
        t, h1 + (size_t)q * BB * HH, Wlc, blin, out,
        ct + (size_t)q * BB * 128);       // -> ct_new
  }
}